// Round 17
// baseline (231.193 us; speedup 1.0000x reference)
//
#include <hip/hip_runtime.h>

typedef __bf16 bf16;
typedef bf16 bf16x2 __attribute__((ext_vector_type(2)));
typedef bf16 bf16x8 __attribute__((ext_vector_type(8)));
typedef float f32x4 __attribute__((ext_vector_type(4)));
typedef unsigned int u32;
typedef unsigned short u16;

#define BB 4
#define SS 4096
#define DD 1024
#define EE 64
static constexpr float SCALE2 = 0.18033688011112042f; // (1/8)*log2(e)
static constexpr float MFIX = 16.0f;                  // fixed softmax shift (log2 domain)

#define MFMA(a,b,c) __builtin_amdgcn_mfma_f32_16x16x32_bf16((a),(b),(c),0,0,0)

typedef __attribute__((address_space(3))) unsigned int lds_u32;
typedef const __attribute__((address_space(1))) unsigned int glb_u32;

static __device__ __forceinline__ void gload16(const void* g, void* l) {
    __builtin_amdgcn_global_load_lds((glb_u32*)g, (lds_u32*)l, 16, 0, 0);
}

static __device__ __forceinline__ u16 f2bf(float x) {
    union { bf16 h; u16 u; } v; v.h = (bf16)x;
    return v.u;
}
static __device__ __forceinline__ u32 pk2(float a, float b) {
    bf16x2 t; t[0] = (bf16)a; t[1] = (bf16)b;
    return __builtin_bit_cast(u32, t);
}
static __device__ __forceinline__ float fexp2(float x) {
    return __builtin_amdgcn_exp2f(x);
}

// ---------------- Kernel 1: SINGLE-PASS prep (unchanged — verified) ----------
__global__ __launch_bounds__(512, 2) void k_prep(const float* __restrict__ enc,
                                                 const float* __restrict__ wq,
                                                 const float* __restrict__ wk,
                                                 u16* __restrict__ qout,
                                                 u16* __restrict__ kout,
                                                 u16* __restrict__ vt) {
    __shared__ __align__(16) u16 la[4096];
    __shared__ __align__(16) u16 lw[8192];
    __shared__ __align__(16) u32 lt[2144];
    const int tid = threadIdx.x;
    const int m0 = blockIdx.x * 64;
    const int bb = m0 >> 12, s0 = m0 & 4095;
    const int w = tid >> 6, lane = tid & 63, l15 = lane & 15, quad = lane >> 4;
    const int ari = tid >> 3, ag = tid & 7;
    const int wri = tid >> 2, wg = (tid & 3) * 2;
    const float* arow = enc + (size_t)(m0 + ari) * DD + ag * 8;
    const float* wrow = ((wri < 64) ? (wq + (size_t)wri * DD) : (wk + (size_t)(wri - 64) * DD)) + (tid & 3) * 16;
    const int tdp = tid >> 3, toct = tid & 7;
    u16* vdst = vt + ((size_t)(bb * DD + 2 * tdp)) * SS + s0 + toct * 8;

    float4 a0 = *(const float4*)(arow);
    float4 a1 = *(const float4*)(arow + 4);
    float4 b0 = *(const float4*)(wrow);
    float4 b1 = *(const float4*)(wrow + 4);
    float4 b2 = *(const float4*)(wrow + 8);
    float4 b3 = *(const float4*)(wrow + 12);

    f32x4 acc[4];
#pragma unroll
    for (int i = 0; i < 4; i++) acc[i] = f32x4{0.f, 0.f, 0.f, 0.f};

    for (int kk = 0; kk < DD; kk += 64) {
        uint4 pa, pw0, pw1;
        pa.x = pk2(a0.x, a0.y); pa.y = pk2(a0.z, a0.w);
        pa.z = pk2(a1.x, a1.y); pa.w = pk2(a1.z, a1.w);
        pw0.x = pk2(b0.x, b0.y); pw0.y = pk2(b0.z, b0.w);
        pw0.z = pk2(b1.x, b1.y); pw0.w = pk2(b1.z, b1.w);
        pw1.x = pk2(b2.x, b2.y); pw1.y = pk2(b2.z, b2.w);
        pw1.z = pk2(b3.x, b3.y); pw1.w = pk2(b3.z, b3.w);
        __syncthreads();
        *(uint4*)&la[ari * 64 + (ag ^ (ari & 7)) * 8] = pa;
        *(uint4*)&lw[wri * 64 + ((wg + 0) ^ (wri & 7)) * 8] = pw0;
        *(uint4*)&lw[wri * 64 + ((wg + 1) ^ (wri & 7)) * 8] = pw1;
        lt[(ag * 4 + 0) * 67 + ari] = pa.x;
        lt[(ag * 4 + 1) * 67 + ari] = pa.y;
        lt[(ag * 4 + 2) * 67 + ari] = pa.z;
        lt[(ag * 4 + 3) * 67 + ari] = pa.w;
        __syncthreads();
        if (kk + 64 < DD) {
            a0 = *(const float4*)(arow + kk + 64);
            a1 = *(const float4*)(arow + kk + 68);
            b0 = *(const float4*)(wrow + kk + 64);
            b1 = *(const float4*)(wrow + kk + 68);
            b2 = *(const float4*)(wrow + kk + 72);
            b3 = *(const float4*)(wrow + kk + 76);
        }
        int m = 16 * (w & 3) + l15;
#pragma unroll
        for (int es = 0; es < 2; es++) {
            bf16x8 af = *(const bf16x8*)&la[m * 64 + ((((es << 2) + quad) ^ (m & 7))) * 8];
#pragma unroll
            for (int ct = 0; ct < 4; ct++) {
                int n = 64 * (w >> 2) + 16 * ct + l15;
                bf16x8 bf_ = *(const bf16x8*)&lw[n * 64 + ((((es << 2) + quad) ^ (n & 7))) * 8];
                acc[ct] = MFMA(af, bf_, acc[ct]);
            }
        }
        if (tid < 256) {
            u32 a_[8];
#pragma unroll
            for (int j = 0; j < 8; j++) a_[j] = lt[tdp * 67 + toct * 8 + j];
            uint4 r0, r1;
            r0.x = (a_[0] & 0xffffu) | (a_[1] << 16);
            r0.y = (a_[2] & 0xffffu) | (a_[3] << 16);
            r0.z = (a_[4] & 0xffffu) | (a_[5] << 16);
            r0.w = (a_[6] & 0xffffu) | (a_[7] << 16);
            r1.x = (a_[0] >> 16) | (a_[1] & 0xffff0000u);
            r1.y = (a_[2] >> 16) | (a_[3] & 0xffff0000u);
            r1.z = (a_[4] >> 16) | (a_[5] & 0xffff0000u);
            r1.w = (a_[6] >> 16) | (a_[7] & 0xffff0000u);
            u16* dst = vdst + (size_t)kk * SS;
            *(uint4*)dst = r0;
            *(uint4*)(dst + SS) = r1;
        }
    }
#pragma unroll
    for (int ct = 0; ct < 4; ct++) {
        int n = 64 * (w >> 2) + 16 * ct + l15;
        u16* dst = (n < 64) ? qout : kout;
        int col = n & 63;
#pragma unroll
        for (int r = 0; r < 4; r++) {
            int grow = m0 + 16 * (w & 3) + 4 * quad + r;
            dst[(size_t)grow * EE + col] = f2bf(acc[ct][r]);
        }
    }
}

// ---------------- Kernel 2: attention v6 -- v5 + counted-vmcnt phase barrier --------
// R14 post-mortem: v5 (4 waves/SIMD) = 114us, Occ 41%, MfmaUtil 33, VALU 46. The
// remaining serial cost: __syncthreads drains vmcnt(0) every phase, serializing the
// 32KB/phase V-DMA (~500-600 cyc at per-CU L2 share) even though V(p+1) is only read
// at phase p+2 (the whole point of lv[3]). v6 (T4, m201-proven pattern): raw s_barrier
// + counted s_waitcnt. Issue order per phase is K,V0,V1 (FIFO): vmcnt(2) drains
// V(p) [needed by pass B(p+1)] and K(p+1) [needed by pass A(p+1)] while leaving
// V(p+1)x2 in flight across the barrier. Tail phases (no new issues) use vmcnt(0).
// lgkmcnt(0) before s_barrier keeps cross-wave lp/lk ds_write visibility.
// Everything else identical to v5.
__global__ __launch_bounds__(1024, 4) void k_attn(const u16* __restrict__ qg, const u16* __restrict__ kg,
                                                  const u16* __restrict__ vt, float* __restrict__ out) {
    __shared__ __align__(16) u16 lds[73984];   // 147968 B -> 1 block/CU
    float* lsum = (float*)&lds[16384];
    const int tid = threadIdx.x;
    const int w = tid >> 6, lane = tid & 63, l15 = lane & 15, quad = lane >> 4;
    // XCD-aware decode (R4/R7/R9-proven: FETCH ~28MB): 256 blocks, round-robin XCDs.
    const int xcd = blockIdx.x & 7;
    const int idx = blockIdx.x >> 3;            // [0,32)
    const int pr = idx & 15;                    // q-tile pair selector
    const int combo = xcd * 2 + (idx >> 4);     // [0,16): 2 combos per XCD
    const int ds = combo & 3, b = combo >> 2;
    const int d0 = ds * 256;
    const int kr = w & 1, qc = w >> 1;   // pass A: 2 k-halves x 8 q-slices(16)
    const int dc = w & 3, qr = w >> 2;   // pass B: 4 d-slices(64) x 4 q-quarters(32)
    const u16* kbase = kg + (size_t)b * SS * EE;
    const u16* vbase = vt + ((size_t)b * DD + d0) * SS;
    const int kgrow = tid >> 3, kglog = (tid & 7) ^ (kgrow & 7);
    const u16* kptr = kbase + (size_t)kgrow * EE + kglog * 8;   // used by tid<512
    // pre-swizzled V global sources (DMA writes linearly, reads XOR by row&7)
    const u16 *vptr0, *vptr1;
    {
        int go0 = tid,        gr0 = go0 >> 3, gl0 = (go0 & 7) ^ (gr0 & 7);
        int go1 = 1024 + tid, gr1 = go1 >> 3, gl1 = (go1 & 7) ^ (gr1 & 7);
        vptr0 = vbase + (size_t)gr0 * SS + gl0 * 8;
        vptr1 = vbase + (size_t)gr1 * SS + gl1 * 8;
    }

    for (int half = 0; half < 2; half++) {
        const int qt = half ? pr : (31 - pr);   // heavy tile first; pair = 68 phases
        const int q0 = qt * 128;
        const int KT = 2 * qt + 2;
        const u16* qbase = qg + ((size_t)b * SS + q0) * EE;
        __syncthreads();   // prior half fully done with all LDS regions (full drain)
        if (tid < 128) lsum[tid] = 0.f;
        // prologue: K(0)->lk[0], V(0)->lv[0] via LDS-DMA
        if (tid < 512) gload16(kptr, (void*)&lds[16640 + tid * 8]);
        gload16(vptr0, (void*)&lds[24832 + (0 * 1024 + tid) * 8]);
        gload16(vptr1, (void*)&lds[24832 + (1 * 1024 + tid) * 8]);
        // Q fragments straight from global (L2-hit): 16 q-rows per wave
        bf16x8 qf0, qf1;
        {
            int qv = 16 * qc + l15;
            qf0 = *(const bf16x8*)(qbase + (size_t)qv * EE + quad * 8);
            qf1 = *(const bf16x8*)(qbase + (size_t)qv * EE + 32 + quad * 8);
        }
        f32x4 o[2][4];
#pragma unroll
        for (int i = 0; i < 2; i++)
#pragma unroll
            for (int j = 0; j < 4; j++) o[i][j] = f32x4{0.f, 0.f, 0.f, 0.f};
        float rl = 0.f;
        __syncthreads();   // prologue staging drained (full), lsum zeros visible

        int sprv = 2, scur = 0, snxt = 1;   // lv slot rotation
        for (int p = 0; p <= KT; p++) {
            // ---- issue DMA for tile p+1: K -> lk[(p+1)&1], V -> lv[snxt] ----
            const bool issued = (p + 1 < KT);
            if (issued) {
                const int k1 = (p + 1) * 64;
                if (tid < 512)
                    gload16(kptr + (size_t)k1 * EE,
                            (void*)&lds[16640 + ((p + 1) & 1) * 4096 + tid * 8]);
                u16* nv = &lds[24832 + snxt * 16384];
                gload16(vptr0 + k1, (void*)&nv[(0 * 1024 + tid) * 8]);
                gload16(vptr1 + k1, (void*)&nv[(1 * 1024 + tid) * 8]);
            }
            // ---- pass A(p): S^T (64k x 128q), exp2, P -> lp[p&1] ----
            if (p < KT) {
                const int k0 = p * 64;
                const u16* lk = &lds[16640 + (p & 1) * 4096];
                u16* lpw = &lds[(p & 1) * 8192];
                const bool dg = (p >= KT - 2);
                const int qv = 16 * qc + l15;
#pragma unroll
                for (int rt = 0; rt < 2; rt++) {
                    int m = 32 * kr + 16 * rt + l15;
                    bf16x8 ka0 = *(const bf16x8*)&lk[m * 64 + ((quad ^ (m & 7))) * 8];
                    bf16x8 ka1 = *(const bf16x8*)&lk[m * 64 + (((4 + quad) ^ (m & 7))) * 8];
                    f32x4 c = f32x4{0.f, 0.f, 0.f, 0.f};
                    c = MFMA(ka0, qf0, c);
                    c = MFMA(ka1, qf1, c);
                    float pv[4];
#pragma unroll
                    for (int r = 0; r < 4; r++) {
                        float arg = __builtin_fmaf(c[r], SCALE2, -MFIX);
                        if (dg) {
                            int kp = k0 + 32 * kr + 16 * rt + 4 * quad + r;
                            if (kp > q0 + qv) arg = -3.0e38f;   // exp2 -> 0
                        }
                        pv[r] = fexp2(arg);
                    }
                    rl += (pv[0] + pv[1]) + (pv[2] + pv[3]);
                    int g16 = 4 * kr + 2 * rt + (quad >> 1);
                    uint2 pkk;
                    pkk.x = pk2(pv[0], pv[1]);
                    pkk.y = pk2(pv[2], pv[3]);
                    *(uint2*)&lpw[qv * 64 + (g16 ^ (qv & 7)) * 8 + (quad & 1) * 4] = pkk;
                }
            }
            // ---- pass B(p-1): O += P * Vt from lp[(p-1)&1] / lv[sprv] ----
            if (p >= 1) {
                const u16* lv = &lds[24832 + sprv * 16384];
                const u16* lpr = &lds[((p - 1) & 1) * 8192];
#pragma unroll
                for (int ks = 0; ks < 2; ks++) {
                    bf16x8 vb[4];
#pragma unroll
                    for (int ct = 0; ct < 4; ct++) {
                        int n = 64 * dc + 16 * ct + l15;
                        vb[ct] = *(const bf16x8*)&lv[n * 64 + ((((ks << 2) + quad) ^ (n & 7))) * 8];
                    }
                    bf16x8 pa[2];
#pragma unroll
                    for (int rt = 0; rt < 2; rt++) {
                        int m = 32 * qr + 16 * rt + l15;
                        pa[rt] = *(const bf16x8*)&lpr[m * 64 + ((((ks << 2) + quad) ^ (m & 7))) * 8];
                    }
                    __builtin_amdgcn_s_setprio(1);
#pragma unroll
                    for (int rt = 0; rt < 2; rt++)
#pragma unroll
                        for (int ct = 0; ct < 4; ct++)
                            o[rt][ct] = MFMA(pa[rt], vb[ct], o[rt][ct]);
                    __builtin_amdgcn_s_setprio(0);
                }
            }
            // ---- counted-vmcnt phase barrier (T4): leave this phase's 2 V-loads in
            // flight (read only at p+2); drain older V(p)+K(p+1) (FIFO). lgkmcnt(0)
            // makes lp/lk ds_writes visible across the barrier.
            if (issued) {
                asm volatile("s_waitcnt vmcnt(2) lgkmcnt(0)\n\ts_barrier" ::: "memory");
            } else {
                asm volatile("s_waitcnt vmcnt(0) lgkmcnt(0)\n\ts_barrier" ::: "memory");
            }
            int t_ = sprv; sprv = scur; scur = snxt; snxt = t_;
        }
        // ---- denominator ----
        {
            float t = rl;
            t += __shfl_xor(t, 16, 64);
            t += __shfl_xor(t, 32, 64);
            if (quad == 0) atomicAdd(&lsum[16 * qc + l15], t);
        }
        __syncthreads();
        // ---- epilogue ----
        float* obase = out + ((size_t)b * SS + q0) * DD + d0 + dc * 64;
#pragma unroll
        for (int rt = 0; rt < 2; rt++) {
#pragma unroll
            for (int r = 0; r < 4; r++) {
                int row = 32 * qr + 16 * rt + 4 * quad + r;
                float li = 1.0f / lsum[row];
#pragma unroll
                for (int ct = 0; ct < 4; ct++)
                    obase[(size_t)row * DD + ct * 16 + l15] = o[rt][ct][r] * li;
            }
        }
    }
}

extern "C" void kernel_launch(void* const* d_in, const int* in_sizes, int n_in,
                              void* d_out, int out_size, void* d_ws, size_t ws_size,
                              hipStream_t stream) {
    (void)in_sizes; (void)n_in; (void)out_size; (void)ws_size;
    const float* enc = (const float*)d_in[0];
    const float* wq = (const float*)d_in[1];
    const float* wk = (const float*)d_in[2];
    char* ws = (char*)d_ws;
    u16* qbf = (u16*)ws;                  // 2 MiB
    u16* kbf = (u16*)(ws + (2ull << 20)); // 2 MiB
    u16* vt  = (u16*)(ws + (4ull << 20)); // 32 MiB
    float* out = (float*)d_out;

    hipLaunchKernelGGL(k_prep, dim3(256), dim3(512), 0, stream, enc, wq, wk, qbf, kbf, vt);
    hipLaunchKernelGGL(k_attn, dim3(256), dim3(1024), 0, stream, qbf, kbf, vt, out);
}

// Round 19
// 219.062 us; speedup vs baseline: 1.0554x; 1.0554x over previous
//
#include <hip/hip_runtime.h>

typedef __bf16 bf16;
typedef bf16 bf16x2 __attribute__((ext_vector_type(2)));
typedef bf16 bf16x8 __attribute__((ext_vector_type(8)));
typedef float f32x4 __attribute__((ext_vector_type(4)));
typedef unsigned int u32;
typedef unsigned short u16;

#define BB 4
#define SS 4096
#define DD 1024
#define EE 64
static constexpr float SCALE2 = 0.18033688011112042f; // (1/8)*log2(e)
static constexpr float MFIX = 16.0f;                  // fixed softmax shift (log2 domain)

#define MFMA(a,b,c) __builtin_amdgcn_mfma_f32_16x16x32_bf16((a),(b),(c),0,0,0)

typedef __attribute__((address_space(3))) unsigned int lds_u32;
typedef const __attribute__((address_space(1))) unsigned int glb_u32;

static __device__ __forceinline__ void gload16(const void* g, void* l) {
    __builtin_amdgcn_global_load_lds((glb_u32*)g, (lds_u32*)l, 16, 0, 0);
}

static __device__ __forceinline__ u16 f2bf(float x) {
    union { bf16 h; u16 u; } v; v.h = (bf16)x;
    return v.u;
}
static __device__ __forceinline__ u32 pk2(float a, float b) {
    bf16x2 t; t[0] = (bf16)a; t[1] = (bf16)b;
    return __builtin_bit_cast(u32, t);
}
static __device__ __forceinline__ float fexp2(float x) {
    return __builtin_amdgcn_exp2f(x);
}

// ---------------- Kernel 1: prep v2 -- 512 blocks (2/CU), role-paired -------------
// R17 analysis: (total - k_attn) = 101-112us across 7 sessions; k_prep never profiled.
// Old prep: 256 blocks = 1 block/CU = 2 waves/SIMD, 16 serial K-iters x 2 barriers x
// 1-deep prefetch -> plausibly ~90-100us (roofline 16-26us). v2 splits the 128 W-rows:
// role 0 = Q projection; role 1 = K projection + vt transpose-out. Blocks i and i+256
// pair on the SAME XCD (i mod 8 equal) so the shared 256KB enc slab stays L2-local.
// Per-block: W-load 16->8 floats/thread (same pattern as A), 8->4 MFMA/iter, acc[2].
// LDS 24.6KB, ~70 VGPR -> 2 blocks/CU (4 waves/SIMD). All LDS swizzles verbatim from
// the verified kernel (lw now uses la's exact write/read pattern).
__global__ __launch_bounds__(512, 2) void k_prep(const float* __restrict__ enc,
                                                 const float* __restrict__ wq,
                                                 const float* __restrict__ wk,
                                                 u16* __restrict__ qout,
                                                 u16* __restrict__ kout,
                                                 u16* __restrict__ vt) {
    __shared__ __align__(16) u16 la[4096];   // A 64x64 bf16, MFMA swizzle
    __shared__ __align__(16) u16 lw[4096];   // W 64x64 bf16 (Q or K half), same swizzle
    __shared__ __align__(16) u32 lt[2144];   // pair-layout transpose, pad 67
    const int tid = threadIdx.x;
    const int role = blockIdx.x >> 8;        // 0 = Q, 1 = K (+ vt out)
    const int m0 = (blockIdx.x & 255) * 64;
    const int bb = m0 >> 12, s0 = m0 & 4095;
    const int w = tid >> 6, lane = tid & 63, l15 = lane & 15, quad = lane >> 4;
    const int ari = tid >> 3, ag = tid & 7;
    const float* arow = enc + (size_t)(m0 + ari) * DD + ag * 8;
    const float* wrow = (role ? wk : wq) + (size_t)ari * DD + ag * 8;
    const int tdp = tid >> 3, toct = tid & 7;
    u16* vdst = vt + ((size_t)(bb * DD + 2 * tdp)) * SS + s0 + toct * 8;

    float4 a0 = *(const float4*)(arow);
    float4 a1 = *(const float4*)(arow + 4);
    float4 b0 = *(const float4*)(wrow);
    float4 b1 = *(const float4*)(wrow + 4);

    f32x4 acc[2];
    acc[0] = f32x4{0.f, 0.f, 0.f, 0.f};
    acc[1] = f32x4{0.f, 0.f, 0.f, 0.f};

    for (int kk = 0; kk < DD; kk += 64) {
        uint4 pa, pw;
        pa.x = pk2(a0.x, a0.y); pa.y = pk2(a0.z, a0.w);
        pa.z = pk2(a1.x, a1.y); pa.w = pk2(a1.z, a1.w);
        pw.x = pk2(b0.x, b0.y); pw.y = pk2(b0.z, b0.w);
        pw.z = pk2(b1.x, b1.y); pw.w = pk2(b1.z, b1.w);
        __syncthreads();   // prior iter done reading la/lw/lt
        *(uint4*)&la[ari * 64 + (ag ^ (ari & 7)) * 8] = pa;
        *(uint4*)&lw[ari * 64 + (ag ^ (ari & 7)) * 8] = pw;
        lt[(ag * 4 + 0) * 67 + ari] = pa.x;
        lt[(ag * 4 + 1) * 67 + ari] = pa.y;
        lt[(ag * 4 + 2) * 67 + ari] = pa.z;
        lt[(ag * 4 + 3) * 67 + ari] = pa.w;
        __syncthreads();
        if (kk + 64 < DD) {
            a0 = *(const float4*)(arow + kk + 64);
            a1 = *(const float4*)(arow + kk + 68);
            b0 = *(const float4*)(wrow + kk + 64);
            b1 = *(const float4*)(wrow + kk + 68);
        }
        int m = 16 * (w & 3) + l15;
#pragma unroll
        for (int es = 0; es < 2; es++) {
            bf16x8 af = *(const bf16x8*)&la[m * 64 + ((((es << 2) + quad) ^ (m & 7))) * 8];
#pragma unroll
            for (int ct = 0; ct < 2; ct++) {
                int n = 16 * ((w >> 2) * 2 + ct) + l15;
                bf16x8 bf_ = *(const bf16x8*)&lw[n * 64 + ((((es << 2) + quad) ^ (n & 7))) * 8];
                acc[ct] = MFMA(af, bf_, acc[ct]);
            }
        }
        // ---- transpose-out (role 1 only): unzip pair rows -> two d-rows ----
        if (role && tid < 256) {
            u32 a_[8];
#pragma unroll
            for (int j = 0; j < 8; j++) a_[j] = lt[tdp * 67 + toct * 8 + j];
            uint4 r0, r1;
            r0.x = (a_[0] & 0xffffu) | (a_[1] << 16);
            r0.y = (a_[2] & 0xffffu) | (a_[3] << 16);
            r0.z = (a_[4] & 0xffffu) | (a_[5] << 16);
            r0.w = (a_[6] & 0xffffu) | (a_[7] << 16);
            r1.x = (a_[0] >> 16) | (a_[1] & 0xffff0000u);
            r1.y = (a_[2] >> 16) | (a_[3] & 0xffff0000u);
            r1.z = (a_[4] >> 16) | (a_[5] & 0xffff0000u);
            r1.w = (a_[6] >> 16) | (a_[7] & 0xffff0000u);
            u16* dst = vdst + (size_t)kk * SS;
            *(uint4*)dst = r0;
            *(uint4*)(dst + SS) = r1;
        }
    }
    u16* dst = role ? kout : qout;
#pragma unroll
    for (int ct = 0; ct < 2; ct++) {
        int n = 16 * ((w >> 2) * 2 + ct) + l15;
#pragma unroll
        for (int r = 0; r < 4; r++) {
            int grow = m0 + 16 * (w & 3) + 4 * quad + r;
            dst[(size_t)grow * EE + n] = f2bf(acc[ct][r]);
        }
    }
}

// ---------------- Kernel 2: attention v5 (reverted from v6) -------------------------
// R17: v6's counted-vmcnt barrier REGRESSED (114.3 -> 123.5us, correctness OK) ->
// the V-DMA drain was not the phase tail. Reverted to the measured-best v5
// (R14: 114.3us, Occ 41%, MfmaUtil 33, VALU 46, VGPR 64, zero spill).
__global__ __launch_bounds__(1024, 4) void k_attn(const u16* __restrict__ qg, const u16* __restrict__ kg,
                                                  const u16* __restrict__ vt, float* __restrict__ out) {
    __shared__ __align__(16) u16 lds[73984];   // 147968 B -> 1 block/CU
    float* lsum = (float*)&lds[16384];
    const int tid = threadIdx.x;
    const int w = tid >> 6, lane = tid & 63, l15 = lane & 15, quad = lane >> 4;
    // XCD-aware decode (R4/R7/R9-proven: FETCH ~28MB): 256 blocks, round-robin XCDs.
    const int xcd = blockIdx.x & 7;
    const int idx = blockIdx.x >> 3;            // [0,32)
    const int pr = idx & 15;                    // q-tile pair selector
    const int combo = xcd * 2 + (idx >> 4);     // [0,16): 2 combos per XCD
    const int ds = combo & 3, b = combo >> 2;
    const int d0 = ds * 256;
    const int kr = w & 1, qc = w >> 1;   // pass A: 2 k-halves x 8 q-slices(16)
    const int dc = w & 3, qr = w >> 2;   // pass B: 4 d-slices(64) x 4 q-quarters(32)
    const u16* kbase = kg + (size_t)b * SS * EE;
    const u16* vbase = vt + ((size_t)b * DD + d0) * SS;
    const int kgrow = tid >> 3, kglog = (tid & 7) ^ (kgrow & 7);
    const u16* kptr = kbase + (size_t)kgrow * EE + kglog * 8;   // used by tid<512
    // pre-swizzled V global sources (DMA writes linearly, reads XOR by row&7)
    const u16 *vptr0, *vptr1;
    {
        int go0 = tid,        gr0 = go0 >> 3, gl0 = (go0 & 7) ^ (gr0 & 7);
        int go1 = 1024 + tid, gr1 = go1 >> 3, gl1 = (go1 & 7) ^ (gr1 & 7);
        vptr0 = vbase + (size_t)gr0 * SS + gl0 * 8;
        vptr1 = vbase + (size_t)gr1 * SS + gl1 * 8;
    }

    for (int half = 0; half < 2; half++) {
        const int qt = half ? pr : (31 - pr);   // heavy tile first; pair = 68 phases
        const int q0 = qt * 128;
        const int KT = 2 * qt + 2;
        const u16* qbase = qg + ((size_t)b * SS + q0) * EE;
        __syncthreads();   // prior half fully done with all LDS regions
        if (tid < 128) lsum[tid] = 0.f;
        // prologue: K(0)->lk[0], V(0)->lv[0] via LDS-DMA
        if (tid < 512) gload16(kptr, (void*)&lds[16640 + tid * 8]);
        gload16(vptr0, (void*)&lds[24832 + (0 * 1024 + tid) * 8]);
        gload16(vptr1, (void*)&lds[24832 + (1 * 1024 + tid) * 8]);
        // Q fragments straight from global (L2-hit): 16 q-rows per wave
        bf16x8 qf0, qf1;
        {
            int qv = 16 * qc + l15;
            qf0 = *(const bf16x8*)(qbase + (size_t)qv * EE + quad * 8);
            qf1 = *(const bf16x8*)(qbase + (size_t)qv * EE + 32 + quad * 8);
        }
        f32x4 o[2][4];
#pragma unroll
        for (int i = 0; i < 2; i++)
#pragma unroll
            for (int j = 0; j < 4; j++) o[i][j] = f32x4{0.f, 0.f, 0.f, 0.f};
        float rl = 0.f;
        __syncthreads();   // prologue staging drained, lsum zeros visible

        int sprv = 2, scur = 0, snxt = 1;   // lv slot rotation
        for (int p = 0; p <= KT; p++) {
            // ---- issue DMA for tile p+1: K -> lk[(p+1)&1], V -> lv[snxt] ----
            if (p + 1 < KT) {
                const int k1 = (p + 1) * 64;
                if (tid < 512)
                    gload16(kptr + (size_t)k1 * EE,
                            (void*)&lds[16640 + ((p + 1) & 1) * 4096 + tid * 8]);
                u16* nv = &lds[24832 + snxt * 16384];
                gload16(vptr0 + k1, (void*)&nv[(0 * 1024 + tid) * 8]);
                gload16(vptr1 + k1, (void*)&nv[(1 * 1024 + tid) * 8]);
            }
            // ---- pass A(p): S^T (64k x 128q), exp2, P -> lp[p&1] ----
            if (p < KT) {
                const int k0 = p * 64;
                const u16* lk = &lds[16640 + (p & 1) * 4096];
                u16* lpw = &lds[(p & 1) * 8192];
                const bool dg = (p >= KT - 2);
                const int qv = 16 * qc + l15;
#pragma unroll
                for (int rt = 0; rt < 2; rt++) {
                    int m = 32 * kr + 16 * rt + l15;
                    bf16x8 ka0 = *(const bf16x8*)&lk[m * 64 + ((quad ^ (m & 7))) * 8];
                    bf16x8 ka1 = *(const bf16x8*)&lk[m * 64 + (((4 + quad) ^ (m & 7))) * 8];
                    f32x4 c = f32x4{0.f, 0.f, 0.f, 0.f};
                    c = MFMA(ka0, qf0, c);
                    c = MFMA(ka1, qf1, c);
                    float pv[4];
#pragma unroll
                    for (int r = 0; r < 4; r++) {
                        float arg = __builtin_fmaf(c[r], SCALE2, -MFIX);
                        if (dg) {
                            int kp = k0 + 32 * kr + 16 * rt + 4 * quad + r;
                            if (kp > q0 + qv) arg = -3.0e38f;   // exp2 -> 0
                        }
                        pv[r] = fexp2(arg);
                    }
                    rl += (pv[0] + pv[1]) + (pv[2] + pv[3]);
                    int g16 = 4 * kr + 2 * rt + (quad >> 1);
                    uint2 pkk;
                    pkk.x = pk2(pv[0], pv[1]);
                    pkk.y = pk2(pv[2], pv[3]);
                    *(uint2*)&lpw[qv * 64 + (g16 ^ (qv & 7)) * 8 + (quad & 1) * 4] = pkk;
                }
            }
            // ---- pass B(p-1): O += P * Vt from lp[(p-1)&1] / lv[sprv] ----
            if (p >= 1) {
                const u16* lv = &lds[24832 + sprv * 16384];
                const u16* lpr = &lds[((p - 1) & 1) * 8192];
#pragma unroll
                for (int ks = 0; ks < 2; ks++) {
                    bf16x8 vb[4];
#pragma unroll
                    for (int ct = 0; ct < 4; ct++) {
                        int n = 64 * dc + 16 * ct + l15;
                        vb[ct] = *(const bf16x8*)&lv[n * 64 + ((((ks << 2) + quad) ^ (n & 7))) * 8];
                    }
                    bf16x8 pa[2];
#pragma unroll
                    for (int rt = 0; rt < 2; rt++) {
                        int m = 32 * qr + 16 * rt + l15;
                        pa[rt] = *(const bf16x8*)&lpr[m * 64 + ((((ks << 2) + quad) ^ (m & 7))) * 8];
                    }
                    __builtin_amdgcn_s_setprio(1);
#pragma unroll
                    for (int rt = 0; rt < 2; rt++)
#pragma unroll
                        for (int ct = 0; ct < 4; ct++)
                            o[rt][ct] = MFMA(pa[rt], vb[ct], o[rt][ct]);
                    __builtin_amdgcn_s_setprio(0);
                }
            }
            __syncthreads();   // single barrier per phase (drains DMA queue too)
            int t_ = sprv; sprv = scur; scur = snxt; snxt = t_;
        }
        // ---- denominator ----
        {
            float t = rl;
            t += __shfl_xor(t, 16, 64);
            t += __shfl_xor(t, 32, 64);
            if (quad == 0) atomicAdd(&lsum[16 * qc + l15], t);
        }
        __syncthreads();
        // ---- epilogue ----
        float* obase = out + ((size_t)b * SS + q0) * DD + d0 + dc * 64;
#pragma unroll
        for (int rt = 0; rt < 2; rt++) {
#pragma unroll
            for (int r = 0; r < 4; r++) {
                int row = 32 * qr + 16 * rt + 4 * quad + r;
                float li = 1.0f / lsum[row];
#pragma unroll
                for (int ct = 0; ct < 4; ct++)
                    obase[(size_t)row * DD + ct * 16 + l15] = o[rt][ct][r] * li;
            }
        }
    }
}

extern "C" void kernel_launch(void* const* d_in, const int* in_sizes, int n_in,
                              void* d_out, int out_size, void* d_ws, size_t ws_size,
                              hipStream_t stream) {
    (void)in_sizes; (void)n_in; (void)out_size; (void)ws_size;
    const float* enc = (const float*)d_in[0];
    const float* wq = (const float*)d_in[1];
    const float* wk = (const float*)d_in[2];
    char* ws = (char*)d_ws;
    u16* qbf = (u16*)ws;                  // 2 MiB
    u16* kbf = (u16*)(ws + (2ull << 20)); // 2 MiB
    u16* vt  = (u16*)(ws + (4ull << 20)); // 32 MiB
    float* out = (float*)d_out;

    hipLaunchKernelGGL(k_prep, dim3(512), dim3(512), 0, stream, enc, wq, wk, qbf, kbf, vt);
    hipLaunchKernelGGL(k_attn, dim3(256), dim3(1024), 0, stream, qbf, kbf, vt, out);
}